// Round 3
// baseline (467.989 us; speedup 1.0000x reference)
//
#include <hip/hip_runtime.h>

typedef unsigned short u16;
typedef unsigned int u32;
typedef __attribute__((ext_vector_type(8))) __bf16 bf16x8;
typedef __attribute__((ext_vector_type(4))) float f32x4;

#define B_  4
#define S_  2048
#define D_  1024
#define H_  16
#define HD_ 64

#define MFMA __builtin_amdgcn_mfma_f32_16x16x32_bf16

__device__ __forceinline__ u16 f2bf(float f) {
  union { float f; u32 u; } v; v.f = f;
  u32 r = v.u + 0x7fffu + ((v.u >> 16) & 1u);
  return (u16)(r >> 16);
}

__device__ __forceinline__ void gld16(const void* g, void* l) {
  __builtin_amdgcn_global_load_lds((__attribute__((address_space(1))) void*)g,
                                   (__attribute__((address_space(3))) void*)l,
                                   16, 0, 0);
}

// pack two fp32 -> one u32 of two bf16 (round-to-nearest)
__device__ __forceinline__ u32 pack_bf(float lo, float hi) {
  u32 a = __builtin_bit_cast(u32, lo) + 0x8000u;
  u32 b = __builtin_bit_cast(u32, hi) + 0x8000u;
  return __builtin_amdgcn_perm(b, a, 0x07060302u);
}

// ---------------- fp32 -> bf16 convert ----------------
__global__ __launch_bounds__(256) void cvt_kernel(const float* __restrict__ src,
                                                  u16* __restrict__ dst, int n) {
  int i = (blockIdx.x * 256 + threadIdx.x) * 4;
  if (i + 3 < n) {
    float4 v = *(const float4*)(src + i);
    ushort4 o;
    o.x = f2bf(v.x); o.y = f2bf(v.y); o.z = f2bf(v.z); o.w = f2bf(v.w);
    *(ushort4*)(dst + i) = o;
  }
}

// ---------------- GEMM: C[r][c] = sum_k A[r][k]*Bm[c][k] ----------------
// 128x128 tile, BK=32, global_load_lds width 16, 4 waves in 2x2.
// mode 0 (QKV): Bm is [3072 x 1024] (Wq;Wk;Wv). col<2048 -> qkOut[row][col]
//               (Q in cols 0..1023, K in 1024..2047); col>=2048 -> V
//               scattered transposed to VtOut[B,H,HD,S].
// mode 1: f32Out[row][col] (final projection)
__global__ __launch_bounds__(256) void gemm_bt(const u16* __restrict__ A,
                                               const u16* __restrict__ Bm,
                                               u16* __restrict__ qkOut,
                                               u16* __restrict__ VtOut,
                                               float* __restrict__ f32Out,
                                               int mode) {
  __shared__ u16 As[128 * 32];
  __shared__ u16 Bs[128 * 32];
  const int t = threadIdx.x, w = t >> 6, l = t & 63;
  const int lrow = l & 15, quad = l >> 4;
  const int wr = w >> 1, wc = w & 1;
  const int r0 = blockIdx.y * 128, c0 = blockIdx.x * 128;
  const int srow = l >> 2, scol = (l & 3) * 8;

  f32x4 acc[4][4] = {};

  for (int k0 = 0; k0 < 1024; k0 += 32) {
#pragma unroll
    for (int j = 0; j < 2; j++) {
      int rowA = 32 * w + 16 * j + srow;
      gld16(A + (size_t)(r0 + rowA) * 1024 + k0 + scol, &As[(32 * w + 16 * j) * 32]);
      gld16(Bm + (size_t)(c0 + rowA) * 1024 + k0 + scol, &Bs[(32 * w + 16 * j) * 32]);
    }
    __syncthreads();

    bf16x8 af[4], bfr[4];
#pragma unroll
    for (int i = 0; i < 4; i++)
      af[i] = *(const bf16x8*)&As[(64 * wr + 16 * i + lrow) * 32 + 8 * quad];
#pragma unroll
    for (int j = 0; j < 4; j++)
      bfr[j] = *(const bf16x8*)&Bs[(64 * wc + 16 * j + lrow) * 32 + 8 * quad];
#pragma unroll
    for (int i = 0; i < 4; i++)
#pragma unroll
      for (int j = 0; j < 4; j++)
        acc[i][j] = MFMA(af[i], bfr[j], acc[i][j], 0, 0, 0);
    __syncthreads();
  }

#pragma unroll
  for (int i = 0; i < 4; i++)
#pragma unroll
    for (int j = 0; j < 4; j++)
#pragma unroll
      for (int rr = 0; rr < 4; rr++) {
        int row = r0 + 64 * wr + 16 * i + 4 * quad + rr;
        int col = c0 + 64 * wc + 16 * j + lrow;
        float v = acc[i][j][rr];
        if (mode == 1) {
          f32Out[(size_t)row * 1024 + col] = v;
        } else {
          u16 bv = f2bf(v);
          if (col < 2048) {
            qkOut[(size_t)row * 2048 + col] = bv;
          } else {
            int cm = col & 1023;
            int hh = cm >> 6, dd = cm & 63, bb = row >> 11, ss = row & 2047;
            VtOut[((size_t)(bb * 16 + hh) * 64 + dd) * 2048 + ss] = bv;
          }
        }
      }
}

// ---------------- Flash attention: no barriers, K/V direct from global ------
// qk: [8192][2048] bf16 (cols 0..1023 = Q, 1024..2047 = K, head h at h*64).
// Vt: [B,H,HD,S] bf16.  Out attnb: [8192][1024] bf16.
// Block: 256 thr = 4 waves; 128 queries/block, 32/wave (2 groups of 16).
// Scores transposed (St = K Q^T) -> softmax per-lane; P is the only LDS
// traffic (wave-private buffer, DS in-order per wave => no __syncthreads).
__global__ __launch_bounds__(256) void attn_kernel(const u16* __restrict__ qk,
                                                   const u16* __restrict__ Vt,
                                                   u16* __restrict__ attnb) {
  __shared__ u16 Ps[4][2][16][72];
  const int t = threadIdx.x, w = t >> 6, l = t & 63;
  const int lrow = l & 15, quad = l >> 4;
  const int b = blockIdx.z, h = blockIdx.y, q0 = blockIdx.x * 128;
  const float C = 0.18033688011f;  // log2(e)/sqrt(64)

  const u16* Qb = qk + ((size_t)b * S_) * 2048 + h * 64;
  // per-lane K base: row lrow, d-offset quad*8 (keys advance by 2048 u16/row)
  const u16* kl = Qb + 1024 + (size_t)lrow * 2048 + quad * 8;
  // per-lane V^T base: d = lrow (+16*nb), key-offset quad*8
  const u16* vl = Vt + ((size_t)(b * H_ + h) * HD_ + lrow) * (size_t)S_ + quad * 8;

  bf16x8 aq[2][2];
#pragma unroll
  for (int g = 0; g < 2; g++)
#pragma unroll
    for (int st = 0; st < 2; st++)
      aq[g][st] = *(const bf16x8*)(Qb + (size_t)(q0 + 32 * w + 16 * g + lrow) * 2048 +
                                   st * 32 + quad * 8);

  float lsum[2] = {0.f, 0.f};
  f32x4 acc[2][4] = {};

  for (int kt = 0; kt < S_ / 64; kt++) {
    // K fragments straight from global (L1/L2-served; tile covered exactly once)
    bf16x8 kf[2][4];
#pragma unroll
    for (int st = 0; st < 2; st++)
#pragma unroll
      for (int nb = 0; nb < 4; nb++)
        kf[st][nb] = *(const bf16x8*)(kl + ((size_t)kt * 64 + 16 * nb) * 2048 + st * 32);

    f32x4 sc[2][4] = {};
#pragma unroll
    for (int st = 0; st < 2; st++)
#pragma unroll
      for (int nb = 0; nb < 4; nb++) {
        sc[0][nb] = MFMA(kf[st][nb], aq[0][st], sc[0][nb], 0, 0, 0);
        sc[1][nb] = MFMA(kf[st][nb], aq[1][st], sc[1][nb], 0, 0, 0);
      }

    // p = exp2(s*C); per-lane partial row-sums; pack 4 keys -> 8B LDS write
#pragma unroll
    for (int g = 0; g < 2; g++)
#pragma unroll
      for (int nb = 0; nb < 4; nb++) {
        float p0 = __builtin_amdgcn_exp2f(sc[g][nb][0] * C);
        float p1 = __builtin_amdgcn_exp2f(sc[g][nb][1] * C);
        float p2 = __builtin_amdgcn_exp2f(sc[g][nb][2] * C);
        float p3 = __builtin_amdgcn_exp2f(sc[g][nb][3] * C);
        lsum[g] += (p0 + p1) + (p2 + p3);
        uint2 pw;
        pw.x = pack_bf(p0, p1);
        pw.y = pack_bf(p2, p3);
        *(uint2*)&Ps[w][g][lrow][16 * nb + 4 * quad] = pw;
      }

    // V fragments from global
    bf16x8 vf[2][4];
#pragma unroll
    for (int st = 0; st < 2; st++)
#pragma unroll
      for (int nb = 0; nb < 4; nb++)
        vf[st][nb] = *(const bf16x8*)(vl + (size_t)(16 * nb) * S_ + kt * 64 + st * 32);

    bf16x8 pf[2][2];
#pragma unroll
    for (int g = 0; g < 2; g++)
#pragma unroll
      for (int st = 0; st < 2; st++)
        pf[g][st] = *(const bf16x8*)&Ps[w][g][lrow][32 * st + 8 * quad];

#pragma unroll
    for (int st = 0; st < 2; st++)
#pragma unroll
      for (int nb = 0; nb < 4; nb++) {
        acc[0][nb] = MFMA(pf[0][st], vf[st][nb], acc[0][nb], 0, 0, 0);
        acc[1][nb] = MFMA(pf[1][st], vf[st][nb], acc[1][nb], 0, 0, 0);
      }
  }

  // full row-sums: quads of the same query are lanes xor 16, 32 apart
#pragma unroll
  for (int g = 0; g < 2; g++) {
    lsum[g] += __shfl_xor(lsum[g], 16, 64);
    lsum[g] += __shfl_xor(lsum[g], 32, 64);
  }
  float linv[2][4];
#pragma unroll
  for (int g = 0; g < 2; g++)
#pragma unroll
    for (int rr = 0; rr < 4; rr++)
      linv[g][rr] = 1.0f / __shfl(lsum[g], 4 * quad + rr, 64);

#pragma unroll
  for (int g = 0; g < 2; g++)
#pragma unroll
    for (int nb = 0; nb < 4; nb++)
#pragma unroll
      for (int rr = 0; rr < 4; rr++) {
        int q = q0 + 32 * w + 16 * g + 4 * quad + rr;
        int dg = h * HD_ + 16 * nb + lrow;
        attnb[((size_t)b * S_ + q) * (size_t)D_ + dg] = f2bf(acc[g][nb][rr] * linv[g][rr]);
      }
}

// ---------------- launcher ----------------
extern "C" void kernel_launch(void* const* d_in, const int* in_sizes, int n_in,
                              void* d_out, int out_size, void* d_ws, size_t ws_size,
                              hipStream_t stream) {
  const float* x  = (const float*)d_in[0];
  const float* Wq = (const float*)d_in[1];
  const float* Wk = (const float*)d_in[2];
  const float* Wv = (const float*)d_in[3];
  const float* Wo = (const float*)d_in[4];
  float* out = (float*)d_out;

  const size_t NX = (size_t)B_ * S_ * D_;  // 8388608
  const size_t NW = (size_t)D_ * D_;       // 1048576
  u16* xb    = (u16*)d_ws;
  u16* wqkv  = xb + NX;          // Wq;Wk;Wv contiguous -> [3072 x 1024]
  u16* wob   = wqkv + 3 * NW;
  u16* qkbuf = wob + NW;         // [8192][2048]: Q | K
  u16* Vt    = qkbuf + 2 * NX;   // [B,H,HD,S]
  u16* attnb = Vt + NX;          // [8192][1024]

  cvt_kernel<<<NX / 1024, 256, 0, stream>>>(x, xb, (int)NX);
  cvt_kernel<<<NW / 1024, 256, 0, stream>>>(Wq, wqkv, (int)NW);
  cvt_kernel<<<NW / 1024, 256, 0, stream>>>(Wk, wqkv + NW, (int)NW);
  cvt_kernel<<<NW / 1024, 256, 0, stream>>>(Wv, wqkv + 2 * NW, (int)NW);
  cvt_kernel<<<NW / 1024, 256, 0, stream>>>(Wo, wob, (int)NW);

  // fused QKV projection: [8192 x 1024] @ [3072 x 1024]^T
  gemm_bt<<<dim3(24, 64), 256, 0, stream>>>(xb, wqkv, qkbuf, Vt, nullptr, 0);

  attn_kernel<<<dim3(S_ / 128, H_, B_), 256, 0, stream>>>(qkbuf, Vt, attnb);

  // output projection
  gemm_bt<<<dim3(8, 64), 256, 0, stream>>>(attnb, wob, nullptr, nullptr, out, 1);
}

// Round 4
// 354.439 us; speedup vs baseline: 1.3204x; 1.3204x over previous
//
#include <hip/hip_runtime.h>

typedef unsigned short u16;
typedef unsigned int u32;
typedef __attribute__((ext_vector_type(8))) __bf16 bf16x8;
typedef __attribute__((ext_vector_type(4))) float f32x4;

#define B_  4
#define S_  2048
#define D_  1024
#define H_  16
#define HD_ 64

#define MFMA __builtin_amdgcn_mfma_f32_16x16x32_bf16

// Swizzled fragment layouts (per (b,h) head-pair, 131072 u16 each):
//  Qf/Kf: element (token s, d) at ((s>>4)*2 + (d>>5))*512
//           + ((s&15) + 16*((d>>3)&3))*8 + (d&7)
//         -> attn loads lane l: 16B @ blk(qb,st)*512 + l*8 giving
//            X[s = qb*16 + (l&15)][d = st*32 + (l>>4)*8 + j]   (MFMA A/B layout)
//  Vf:    element (d, token s) at ((s>>5)*4 + (d>>4))*512
//           + ((d&15) + 16*((s>>3)&3))*8 + (s&7)
//         -> attn loads lane l: 16B @ blk(kc,db)*512 + l*8 giving
//            V^T[d = db*16 + (l&15)][key = kc*32 + (l>>4)*8 + j] (MFMA B layout)

__device__ __forceinline__ u16 f2bf(float f) {
  union { float f; u32 u; } v; v.f = f;
  u32 r = v.u + 0x7fffu + ((v.u >> 16) & 1u);
  return (u16)(r >> 16);
}

__device__ __forceinline__ void gld16(const void* g, void* l) {
  __builtin_amdgcn_global_load_lds((__attribute__((address_space(1))) void*)g,
                                   (__attribute__((address_space(3))) void*)l,
                                   16, 0, 0);
}

// pack two fp32 -> one u32 of two bf16 (round-to-nearest); low u16 = lo
__device__ __forceinline__ u32 pack_bf(float lo, float hi) {
  u32 a = __builtin_bit_cast(u32, lo) + 0x8000u;
  u32 b = __builtin_bit_cast(u32, hi) + 0x8000u;
  return __builtin_amdgcn_perm(b, a, 0x07060302u);
}

// ---------------- fp32 -> bf16 converts ----------------
__global__ __launch_bounds__(256) void cvt_kernel(const float* __restrict__ src,
                                                  u16* __restrict__ dst, int n) {
  int i = (blockIdx.x * 256 + threadIdx.x) * 4;
  if (i + 3 < n) {
    float4 v = *(const float4*)(src + i);
    ushort4 o;
    o.x = f2bf(v.x); o.y = f2bf(v.y); o.z = f2bf(v.z); o.w = f2bf(v.w);
    *(ushort4*)(dst + i) = o;
  }
}

__global__ __launch_bounds__(256) void cvt4_kernel(const float* __restrict__ s0,
                                                   const float* __restrict__ s1,
                                                   const float* __restrict__ s2,
                                                   const float* __restrict__ s3,
                                                   u16* __restrict__ dst) {
  const float* srcs[4] = {s0, s1, s2, s3};
  const float* src = srcs[blockIdx.y];
  u16* d = dst + (size_t)blockIdx.y * (D_ * D_);
  int i = (blockIdx.x * 256 + threadIdx.x) * 4;
  float4 v = *(const float4*)(src + i);
  ushort4 o;
  o.x = f2bf(v.x); o.y = f2bf(v.y); o.z = f2bf(v.z); o.w = f2bf(v.w);
  *(ushort4*)(d + i) = o;
}

// ---------------- GEMM: C[r][c] = sum_k A[r][k]*Bm[c][k] ----------------
// 128x128 tile, BK=32, global_load_lds width 16, 4 waves in 2x2.
// mode 0 (QKV): Bm = [3072 x 1024] (Wq;Wk;Wv); writes swizzled Qf/Kf/Vf.
// mode 1: f32Out[row][col] (final projection).
__global__ __launch_bounds__(256) void gemm_bt(const u16* __restrict__ A,
                                               const u16* __restrict__ Bm,
                                               u16* __restrict__ Qfp,
                                               u16* __restrict__ Kfp,
                                               u16* __restrict__ Vfp,
                                               float* __restrict__ f32Out,
                                               int mode) {
  __shared__ u16 As[128 * 32];
  __shared__ u16 Bs[128 * 32];
  const int t = threadIdx.x, w = t >> 6, l = t & 63;
  const int lrow = l & 15, quad = l >> 4;
  const int wr = w >> 1, wc = w & 1;
  const int r0 = blockIdx.y * 128, c0 = blockIdx.x * 128;
  const int srow = l >> 2, scol = (l & 3) * 8;

  f32x4 acc[4][4] = {};

  for (int k0 = 0; k0 < 1024; k0 += 32) {
#pragma unroll
    for (int j = 0; j < 2; j++) {
      int rowA = 32 * w + 16 * j + srow;
      gld16(A + (size_t)(r0 + rowA) * 1024 + k0 + scol, &As[(32 * w + 16 * j) * 32]);
      gld16(Bm + (size_t)(c0 + rowA) * 1024 + k0 + scol, &Bs[(32 * w + 16 * j) * 32]);
    }
    __syncthreads();

    bf16x8 af[4], bfr[4];
#pragma unroll
    for (int i = 0; i < 4; i++)
      af[i] = *(const bf16x8*)&As[(64 * wr + 16 * i + lrow) * 32 + 8 * quad];
#pragma unroll
    for (int j = 0; j < 4; j++)
      bfr[j] = *(const bf16x8*)&Bs[(64 * wc + 16 * j + lrow) * 32 + 8 * quad];
#pragma unroll
    for (int i = 0; i < 4; i++)
#pragma unroll
      for (int j = 0; j < 4; j++)
        acc[i][j] = MFMA(af[i], bfr[j], acc[i][j], 0, 0, 0);
    __syncthreads();
  }

  if (mode == 1) {
#pragma unroll
    for (int i = 0; i < 4; i++)
#pragma unroll
      for (int j = 0; j < 4; j++)
#pragma unroll
        for (int rr = 0; rr < 4; rr++) {
          int row = r0 + 64 * wr + 16 * i + 4 * quad + rr;
          int col = c0 + 64 * wc + 16 * j + lrow;
          f32Out[(size_t)row * 1024 + col] = acc[i][j][rr];
        }
    return;
  }

  // mode 0: mat uniform per block (col-block boundaries align with 1024)
  const int mat = c0 >> 10;                     // 0=Q 1=K 2=V
  const int hh = ((c0 & 1023) >> 6) + wc;       // head, wave-uniform
  const int bb = r0 >> 11;                      // batch, block-uniform
  const int S0 = (r0 & 2047) + 64 * wr;         // token base, mult of 64
  u16* hb = (mat == 0 ? Qfp : (mat == 1 ? Kfp : Vfp)) +
            (size_t)(bb * 16 + hh) * 131072;

  if (mat < 2) {
    const int c_l = quad * 32 + (lrow & 7);
    const int R16 = S0 >> 4;
#pragma unroll
    for (int i = 0; i < 4; i++)
#pragma unroll
      for (int j = 0; j < 4; j++) {
        int oj = (j >> 1) * 512 + ((2 * j + (lrow >> 3)) & 3) * 128;
        u16* p = hb + (R16 + i) * 1024 + oj + c_l;
#pragma unroll
        for (int rr = 0; rr < 4; rr++) p[rr * 8] = f2bf(acc[i][j][rr]);
      }
  } else {
#pragma unroll
    for (int i = 0; i < 4; i++) {
      int blkr = ((S0 >> 5) + ((4 * i + quad) >> 3)) * 4;
      int lanew = (lrow + 16 * ((2 * i + (quad >> 1)) & 3)) * 8 + 4 * (quad & 1);
#pragma unroll
      for (int j = 0; j < 4; j++) {
        uint2 pw;
        pw.x = pack_bf(acc[i][j][0], acc[i][j][1]);
        pw.y = pack_bf(acc[i][j][2], acc[i][j][3]);
        *(uint2*)(hb + (blkr + j) * 512 + lanew) = pw;
      }
    }
  }
}

// ---------------- Flash attention: barrier-free, fragment-swizzled inputs ---
// Qf/Kf/Vf: swizzled per-head fragment layout (see top). Out: [B*S][D] bf16.
// Block: 256 thr = 4 waves; 128 queries/block, 32/wave (2 groups of 16).
// Scores transposed (St = K Q^T) -> softmax per-lane. P via per-wave LDS in a
// conflict-free layout; no __syncthreads anywhere in the loop.
__global__ __launch_bounds__(256) void attn_kernel(const u16* __restrict__ Qf,
                                                   const u16* __restrict__ Kf,
                                                   const u16* __restrict__ Vf,
                                                   u16* __restrict__ attnb) {
  __shared__ uint2 Ps[4][2][4][16][4];   // [wave][g][key16][query][key4] 16 KB
  const int t = threadIdx.x, w = t >> 6, l = t & 63;
  const int lrow = l & 15, quad = l >> 4;
  // XCD-aware decode: block n -> XCD n%8; give each XCD 8 (b,h) pairs
  const int f = blockIdx.x;
  const int bh = (f & 7) * 8 + (f >> 7);
  const int qb0 = (f >> 3) & 15;
  const int b = bh >> 4, h = bh & 15;
  const int q0 = qb0 * 128;
  const float C = 0.18033688011f;  // log2(e)/sqrt(64)

  const u16* Qh = Qf + (size_t)bh * 131072;
  const u16* kp = Kf + (size_t)bh * 131072 + l * 8;
  const u16* vp = Vf + (size_t)bh * 131072 + l * 8;

  bf16x8 aq[2][2];
#pragma unroll
  for (int g = 0; g < 2; g++) {
    int qb = qb0 * 8 + 2 * w + g;
#pragma unroll
    for (int st = 0; st < 2; st++)
      aq[g][st] = *(const bf16x8*)(Qh + (qb * 2 + st) * 512 + l * 8);
  }

  float lsum[2] = {0.f, 0.f};
  f32x4 acc[2][4] = {};

  for (int kt = 0; kt < S_ / 64; kt++) {
    // coalesced fragment loads: per iter 8 KB contiguous for K and for V
    bf16x8 kf[2][4], vf[2][4];
#pragma unroll
    for (int st = 0; st < 2; st++)
#pragma unroll
      for (int nb = 0; nb < 4; nb++)
        kf[st][nb] = *(const bf16x8*)(kp + (nb * 2 + st) * 512);
#pragma unroll
    for (int st = 0; st < 2; st++)
#pragma unroll
      for (int nb = 0; nb < 4; nb++)
        vf[st][nb] = *(const bf16x8*)(vp + (st * 4 + nb) * 512);
    kp += 4096;
    vp += 4096;

    // St = K Q^T : lane holds keys 16nb+4quad+rr for query lrow
    f32x4 sc[2][4] = {};
#pragma unroll
    for (int st = 0; st < 2; st++)
#pragma unroll
      for (int nb = 0; nb < 4; nb++) {
        sc[0][nb] = MFMA(kf[st][nb], aq[0][st], sc[0][nb], 0, 0, 0);
        sc[1][nb] = MFMA(kf[st][nb], aq[1][st], sc[1][nb], 0, 0, 0);
      }

    // p = exp2(s*C); per-lane partial row-sums; conflict-free 8B LDS writes
#pragma unroll
    for (int g = 0; g < 2; g++)
#pragma unroll
      for (int nb = 0; nb < 4; nb++) {
        float p0 = __builtin_amdgcn_exp2f(sc[g][nb][0] * C);
        float p1 = __builtin_amdgcn_exp2f(sc[g][nb][1] * C);
        float p2 = __builtin_amdgcn_exp2f(sc[g][nb][2] * C);
        float p3 = __builtin_amdgcn_exp2f(sc[g][nb][3] * C);
        lsum[g] += (p0 + p1) + (p2 + p3);
        uint2 pw;
        pw.x = pack_bf(p0, p1);
        pw.y = pack_bf(p2, p3);
        Ps[w][g][nb][lrow][quad] = pw;
      }

    // P back in A-layout: 16B reads, two contiguous 512B regions per instr
    bf16x8 pf[2][2];
#pragma unroll
    for (int g = 0; g < 2; g++)
#pragma unroll
      for (int st = 0; st < 2; st++)
        pf[g][st] = *(const bf16x8*)&Ps[w][g][2 * st + (quad >> 1)][lrow][2 * (quad & 1)];

    // O += P V
#pragma unroll
    for (int st = 0; st < 2; st++)
#pragma unroll
      for (int nb = 0; nb < 4; nb++) {
        acc[0][nb] = MFMA(pf[0][st], vf[st][nb], acc[0][nb], 0, 0, 0);
        acc[1][nb] = MFMA(pf[1][st], vf[st][nb], acc[1][nb], 0, 0, 0);
      }
  }

  // full row-sums: the 4 quads of a query are lanes xor 16, 32 apart
#pragma unroll
  for (int g = 0; g < 2; g++) {
    lsum[g] += __shfl_xor(lsum[g], 16, 64);
    lsum[g] += __shfl_xor(lsum[g], 32, 64);
  }
  float linv[2][4];
#pragma unroll
  for (int g = 0; g < 2; g++)
#pragma unroll
    for (int rr = 0; rr < 4; rr++)
      linv[g][rr] = 1.0f / __shfl(lsum[g], 4 * quad + rr, 64);

#pragma unroll
  for (int g = 0; g < 2; g++)
#pragma unroll
    for (int nb = 0; nb < 4; nb++)
#pragma unroll
      for (int rr = 0; rr < 4; rr++) {
        int q = q0 + 32 * w + 16 * g + 4 * quad + rr;
        int dg = h * HD_ + 16 * nb + lrow;
        attnb[((size_t)b * S_ + q) * (size_t)D_ + dg] = f2bf(acc[g][nb][rr] * linv[g][rr]);
      }
}

// ---------------- launcher ----------------
extern "C" void kernel_launch(void* const* d_in, const int* in_sizes, int n_in,
                              void* d_out, int out_size, void* d_ws, size_t ws_size,
                              hipStream_t stream) {
  const float* x  = (const float*)d_in[0];
  const float* Wq = (const float*)d_in[1];
  const float* Wk = (const float*)d_in[2];
  const float* Wv = (const float*)d_in[3];
  const float* Wo = (const float*)d_in[4];
  float* out = (float*)d_out;

  const size_t NX = (size_t)B_ * S_ * D_;  // 8388608
  const size_t NW = (size_t)D_ * D_;       // 1048576
  u16* xb    = (u16*)d_ws;
  u16* wall  = xb + NX;           // Wq;Wk;Wv;Wo -> [4096 x 1024]
  u16* Qf    = wall + 4 * NW;     // swizzled fragment buffers
  u16* Kf    = Qf + NX;
  u16* Vf    = Kf + NX;
  u16* attnb = Vf + NX;           // [8192][1024]

  cvt_kernel<<<NX / 1024, 256, 0, stream>>>(x, xb, (int)NX);
  cvt4_kernel<<<dim3(NW / 1024, 4), 256, 0, stream>>>(Wq, Wk, Wv, Wo, wall);

  // fused QKV projection: [8192 x 1024] @ [3072 x 1024]^T -> swizzled Q/K/V
  gemm_bt<<<dim3(24, 64), 256, 0, stream>>>(xb, wall, Qf, Kf, Vf, nullptr, 0);

  attn_kernel<<<dim3(1024), 256, 0, stream>>>(Qf, Kf, Vf, attnb);

  // output projection
  gemm_bt<<<dim3(8, 64), 256, 0, stream>>>(attnb, wall + 3 * NW, nullptr, nullptr,
                                           nullptr, out, 1);
}

// Round 5
// 303.477 us; speedup vs baseline: 1.5421x; 1.1679x over previous
//
#include <hip/hip_runtime.h>

typedef unsigned short u16;
typedef unsigned int u32;
typedef __attribute__((ext_vector_type(8))) __bf16 bf16x8;
typedef __attribute__((ext_vector_type(4))) float f32x4;

#define B_  4
#define S_  2048
#define D_  1024
#define H_  16
#define HD_ 64

#define MFMA __builtin_amdgcn_mfma_f32_16x16x32_bf16

// Swizzled fragment layouts (per (b,h) head, 131072 u16 each):
//  Qf/Kf: element (token s, d) at ((s>>4)*2 + (d>>5))*512
//           + ((s&15) + 16*((d>>3)&3))*8 + (d&7)
//         -> lane l loads 16B @ blk*512 + l*8 = MFMA A/B fragment
//  Vf:    element (d, token s) at ((s>>5)*4 + (d>>4))*512
//           + ((d&15) + 16*((s>>3)&3))*8 + (s&7)

__device__ __forceinline__ u16 f2bf(float f) {
  union { float f; u32 u; } v; v.f = f;
  u32 r = v.u + 0x7fffu + ((v.u >> 16) & 1u);
  return (u16)(r >> 16);
}

__device__ __forceinline__ void gld16(const void* g, void* l) {
  __builtin_amdgcn_global_load_lds((__attribute__((address_space(1))) void*)g,
                                   (__attribute__((address_space(3))) void*)l,
                                   16, 0, 0);
}

__device__ __forceinline__ u32 pack_bf(float lo, float hi) {
  u32 a = __builtin_bit_cast(u32, lo) + 0x8000u;
  u32 b = __builtin_bit_cast(u32, hi) + 0x8000u;
  return __builtin_amdgcn_perm(b, a, 0x07060302u);
}

// ---------------- fp32 -> bf16 converts ----------------
__global__ __launch_bounds__(256) void cvt_kernel(const float* __restrict__ src,
                                                  u16* __restrict__ dst, int n) {
  int i = (blockIdx.x * 256 + threadIdx.x) * 4;
  if (i + 3 < n) {
    float4 v = *(const float4*)(src + i);
    ushort4 o;
    o.x = f2bf(v.x); o.y = f2bf(v.y); o.z = f2bf(v.z); o.w = f2bf(v.w);
    *(ushort4*)(dst + i) = o;
  }
}

__global__ __launch_bounds__(256) void cvt4_kernel(const float* __restrict__ s0,
                                                   const float* __restrict__ s1,
                                                   const float* __restrict__ s2,
                                                   const float* __restrict__ s3,
                                                   u16* __restrict__ dst) {
  const float* srcs[4] = {s0, s1, s2, s3};
  const float* src = srcs[blockIdx.y];
  u16* d = dst + (size_t)blockIdx.y * (D_ * D_);
  int i = (blockIdx.x * 256 + threadIdx.x) * 4;
  float4 v = *(const float4*)(src + i);
  ushort4 o;
  o.x = f2bf(v.x); o.y = f2bf(v.y); o.z = f2bf(v.z); o.w = f2bf(v.w);
  *(ushort4*)(d + i) = o;
}

// ---------------- GEMM: C[r][c] = sum_k A[r][k]*Bm[c][k] ----------------
// 128x128 tile, BK=32, global_load_lds width 16, 4 waves in 2x2.
// mode 0 (QKV): Bm = [3072 x 1024] (Wq;Wk;Wv); writes swizzled Qf/Kf/Vf.
// mode 1: f32Out[row][col] (final projection).
__global__ __launch_bounds__(256) void gemm_bt(const u16* __restrict__ A,
                                               const u16* __restrict__ Bm,
                                               u16* __restrict__ Qfp,
                                               u16* __restrict__ Kfp,
                                               u16* __restrict__ Vfp,
                                               float* __restrict__ f32Out,
                                               int mode) {
  __shared__ u16 As[128 * 32];
  __shared__ u16 Bs[128 * 32];
  const int t = threadIdx.x, w = t >> 6, l = t & 63;
  const int lrow = l & 15, quad = l >> 4;
  const int wr = w >> 1, wc = w & 1;
  const int r0 = blockIdx.y * 128, c0 = blockIdx.x * 128;
  const int srow = l >> 2, scol = (l & 3) * 8;

  f32x4 acc[4][4] = {};

  for (int k0 = 0; k0 < 1024; k0 += 32) {
#pragma unroll
    for (int j = 0; j < 2; j++) {
      int rowA = 32 * w + 16 * j + srow;
      gld16(A + (size_t)(r0 + rowA) * 1024 + k0 + scol, &As[(32 * w + 16 * j) * 32]);
      gld16(Bm + (size_t)(c0 + rowA) * 1024 + k0 + scol, &Bs[(32 * w + 16 * j) * 32]);
    }
    __syncthreads();

    bf16x8 af[4], bfr[4];
#pragma unroll
    for (int i = 0; i < 4; i++)
      af[i] = *(const bf16x8*)&As[(64 * wr + 16 * i + lrow) * 32 + 8 * quad];
#pragma unroll
    for (int j = 0; j < 4; j++)
      bfr[j] = *(const bf16x8*)&Bs[(64 * wc + 16 * j + lrow) * 32 + 8 * quad];
#pragma unroll
    for (int i = 0; i < 4; i++)
#pragma unroll
      for (int j = 0; j < 4; j++)
        acc[i][j] = MFMA(af[i], bfr[j], acc[i][j], 0, 0, 0);
    __syncthreads();
  }

  if (mode == 1) {
#pragma unroll
    for (int i = 0; i < 4; i++)
#pragma unroll
      for (int j = 0; j < 4; j++)
#pragma unroll
        for (int rr = 0; rr < 4; rr++) {
          int row = r0 + 64 * wr + 16 * i + 4 * quad + rr;
          int col = c0 + 64 * wc + 16 * j + lrow;
          f32Out[(size_t)row * 1024 + col] = acc[i][j][rr];
        }
    return;
  }

  // mode 0: mat uniform per block (col-block boundaries align with 1024)
  const int mat = c0 >> 10;                     // 0=Q 1=K 2=V
  const int hh = ((c0 & 1023) >> 6) + wc;       // head, wave-uniform
  const int bb = r0 >> 11;                      // batch, block-uniform
  const int S0 = (r0 & 2047) + 64 * wr;         // token base, mult of 64
  u16* hb = (mat == 0 ? Qfp : (mat == 1 ? Kfp : Vfp)) +
            (size_t)(bb * 16 + hh) * 131072;

  if (mat < 2) {
    // per-wave LDS transpose: C-layout scalars -> fragment layout -> wide store
    u16* scr = As + w * 1024;   // 2KB per wave, wave-private (no barrier needed)
    const int R16 = S0 >> 4;
#pragma unroll
    for (int i = 0; i < 4; i++) {
#pragma unroll
      for (int j = 0; j < 4; j++) {
        int oj = (j >> 1) * 512 + ((2 * j + (lrow >> 3)) & 3) * 128 +
                 quad * 32 + (lrow & 7);
#pragma unroll
        for (int rr = 0; rr < 4; rr++) scr[oj + rr * 8] = f2bf(acc[i][j][rr]);
      }
      uint4 o0 = *(const uint4*)(scr + l * 8);          // DS in-order per wave
      uint4 o1 = *(const uint4*)(scr + 512 + l * 8);
      *(uint4*)(hb + (size_t)(R16 + i) * 1024 + l * 8) = o0;
      *(uint4*)(hb + (size_t)(R16 + i) * 1024 + 512 + l * 8) = o1;
    }
  } else {
#pragma unroll
    for (int i = 0; i < 4; i++) {
      int blkr = ((S0 >> 5) + ((4 * i + quad) >> 3)) * 4;
      int lanew = (lrow + 16 * ((2 * i + (quad >> 1)) & 3)) * 8 + 4 * (quad & 1);
#pragma unroll
      for (int j = 0; j < 4; j++) {
        uint2 pw;
        pw.x = pack_bf(acc[i][j][0], acc[i][j][1]);
        pw.y = pack_bf(acc[i][j][2], acc[i][j][3]);
        *(uint2*)(hb + (blkr + j) * 512 + lanew) = pw;
      }
    }
  }
}

// ---------------- Flash attention: barrier-free, prefetched fragments ------
// Block: 256 thr = 4 waves; 128 queries/block, 32/wave (2 groups of 16).
// Scores transposed (St = K Q^T) -> softmax per-lane. K/V fragments register-
// prefetched one kt-iteration ahead; P via conflict-free per-wave LDS.
__global__ __launch_bounds__(256, 2) void attn_kernel(const u16* __restrict__ Qf,
                                                      const u16* __restrict__ Kf,
                                                      const u16* __restrict__ Vf,
                                                      u16* __restrict__ attnb) {
  __shared__ uint2 Ps[4][2][4][16][4];   // [wave][g][key16][query][key4] 16 KB
  const int t = threadIdx.x, w = t >> 6, l = t & 63;
  const int lrow = l & 15, quad = l >> 4;
  const int f = blockIdx.x;
  const int bh = (f & 7) * 8 + (f >> 7);   // 8 heads per XCD (L2 locality)
  const int qb0 = (f >> 3) & 15;
  const int b = bh >> 4, h = bh & 15;
  const int q0 = qb0 * 128;
  const float C = 0.18033688011f;  // log2(e)/sqrt(64)

  const u16* Qh = Qf + (size_t)bh * 131072;
  const u16* kp = Kf + (size_t)bh * 131072 + l * 8;
  const u16* vp = Vf + (size_t)bh * 131072 + l * 8;

  bf16x8 aq[2][2];
#pragma unroll
  for (int g = 0; g < 2; g++) {
    int qb = qb0 * 8 + 2 * w + g;
#pragma unroll
    for (int st = 0; st < 2; st++)
      aq[g][st] = *(const bf16x8*)(Qh + (qb * 2 + st) * 512 + l * 8);
  }

  float lsum[2] = {0.f, 0.f};
  f32x4 acc[2][4] = {};

  // preload kt=0 fragments
  bf16x8 kc[2][4], vc[2][4];
#pragma unroll
  for (int st = 0; st < 2; st++)
#pragma unroll
    for (int nb = 0; nb < 4; nb++) {
      kc[st][nb] = *(const bf16x8*)(kp + (nb * 2 + st) * 512);
      vc[st][nb] = *(const bf16x8*)(vp + (st * 4 + nb) * 512);
    }

#pragma unroll 2
  for (int kt = 0; kt < S_ / 64; kt++) {
    kp += 4096; vp += 4096;
    // prefetch kt+1 (unconditional; harmless 8KB over-read past last tile)
    bf16x8 kn[2][4], vn[2][4];
#pragma unroll
    for (int st = 0; st < 2; st++)
#pragma unroll
      for (int nb = 0; nb < 4; nb++) {
        kn[st][nb] = *(const bf16x8*)(kp + (nb * 2 + st) * 512);
        vn[st][nb] = *(const bf16x8*)(vp + (st * 4 + nb) * 512);
      }

    // St = K Q^T : lane holds keys 16nb+4quad+rr for query lrow
    f32x4 sc[2][4] = {};
#pragma unroll
    for (int st = 0; st < 2; st++)
#pragma unroll
      for (int nb = 0; nb < 4; nb++) {
        sc[0][nb] = MFMA(kc[st][nb], aq[0][st], sc[0][nb], 0, 0, 0);
        sc[1][nb] = MFMA(kc[st][nb], aq[1][st], sc[1][nb], 0, 0, 0);
      }

    // p = exp2(s*C); per-lane partial row-sums; conflict-free 8B LDS writes
#pragma unroll
    for (int g = 0; g < 2; g++)
#pragma unroll
      for (int nb = 0; nb < 4; nb++) {
        float p0 = __builtin_amdgcn_exp2f(sc[g][nb][0] * C);
        float p1 = __builtin_amdgcn_exp2f(sc[g][nb][1] * C);
        float p2 = __builtin_amdgcn_exp2f(sc[g][nb][2] * C);
        float p3 = __builtin_amdgcn_exp2f(sc[g][nb][3] * C);
        lsum[g] += (p0 + p1) + (p2 + p3);
        uint2 pw;
        pw.x = pack_bf(p0, p1);
        pw.y = pack_bf(p2, p3);
        Ps[w][g][nb][lrow][quad] = pw;
      }

    // P back in A-layout: 16B reads, conflict-free
    bf16x8 pf[2][2];
#pragma unroll
    for (int g = 0; g < 2; g++)
#pragma unroll
      for (int st = 0; st < 2; st++)
        pf[g][st] = *(const bf16x8*)&Ps[w][g][2 * st + (quad >> 1)][lrow][2 * (quad & 1)];

    // O += P V
#pragma unroll
    for (int st = 0; st < 2; st++)
#pragma unroll
      for (int nb = 0; nb < 4; nb++) {
        acc[0][nb] = MFMA(pf[0][st], vc[st][nb], acc[0][nb], 0, 0, 0);
        acc[1][nb] = MFMA(pf[1][st], vc[st][nb], acc[1][nb], 0, 0, 0);
      }

    // rotate prefetched fragments (free under unroll-2 register renaming)
#pragma unroll
    for (int st = 0; st < 2; st++)
#pragma unroll
      for (int nb = 0; nb < 4; nb++) {
        kc[st][nb] = kn[st][nb];
        vc[st][nb] = vn[st][nb];
      }
  }

  // full row-sums: the 4 quads of a query are lanes xor 16, 32 apart
#pragma unroll
  for (int g = 0; g < 2; g++) {
    lsum[g] += __shfl_xor(lsum[g], 16, 64);
    lsum[g] += __shfl_xor(lsum[g], 32, 64);
  }
  float linv[2][4];
#pragma unroll
  for (int g = 0; g < 2; g++)
#pragma unroll
    for (int rr = 0; rr < 4; rr++)
      linv[g][rr] = 1.0f / __shfl(lsum[g], 4 * quad + rr, 64);

#pragma unroll
  for (int g = 0; g < 2; g++)
#pragma unroll
    for (int nb = 0; nb < 4; nb++)
#pragma unroll
      for (int rr = 0; rr < 4; rr++) {
        int q = q0 + 32 * w + 16 * g + 4 * quad + rr;
        int dg = h * HD_ + 16 * nb + lrow;
        attnb[((size_t)b * S_ + q) * (size_t)D_ + dg] = f2bf(acc[g][nb][rr] * linv[g][rr]);
      }
}

// ---------------- launcher ----------------
extern "C" void kernel_launch(void* const* d_in, const int* in_sizes, int n_in,
                              void* d_out, int out_size, void* d_ws, size_t ws_size,
                              hipStream_t stream) {
  const float* x  = (const float*)d_in[0];
  const float* Wq = (const float*)d_in[1];
  const float* Wk = (const float*)d_in[2];
  const float* Wv = (const float*)d_in[3];
  const float* Wo = (const float*)d_in[4];
  float* out = (float*)d_out;

  const size_t NX = (size_t)B_ * S_ * D_;  // 8388608
  const size_t NW = (size_t)D_ * D_;       // 1048576
  u16* xb    = (u16*)d_ws;
  u16* wall  = xb + NX;           // Wq;Wk;Wv;Wo -> [4096 x 1024]
  u16* Qf    = wall + 4 * NW;     // swizzled fragment buffers
  u16* Kf    = Qf + NX;
  u16* Vf    = Kf + NX;
  u16* attnb = Vf + NX;           // [8192][1024]

  cvt_kernel<<<NX / 1024, 256, 0, stream>>>(x, xb, (int)NX);
  cvt4_kernel<<<dim3(NW / 1024, 4), 256, 0, stream>>>(Wq, Wk, Wv, Wo, wall);

  // fused QKV projection: [8192 x 1024] @ [3072 x 1024]^T -> swizzled Q/K/V
  gemm_bt<<<dim3(24, 64), 256, 0, stream>>>(xb, wall, Qf, Kf, Vf, nullptr, 0);

  attn_kernel<<<dim3(1024), 256, 0, stream>>>(Qf, Kf, Vf, attnb);

  // output projection
  gemm_bt<<<dim3(8, 64), 256, 0, stream>>>(attnb, wall + 3 * NW, nullptr, nullptr,
                                           nullptr, out, 1);
}